// Round 7
// baseline (285.135 us; speedup 1.0000x reference)
//
#include <hip/hip_runtime.h>
#include <hip/hip_fp16.h>
#include <math.h>

#define N_NODES 50000
#define N_EDGES 800000
#define VOCAB 100
#define DIM 128
#define N_GRAPHS 512
#define LN_EPS 1e-5f
#define CAP 64    // slot capacity per node (deg~Poisson(16); P(>=64)~e^-125)
#define SEG 4     // nodes per wave in k_agg2 (50000 % 4 == 0)
#define NWIN 8    // dst windows (== XCDs)
#define WSZ (N_NODES / NWIN)     // 6250 nodes per window (exact)
#define W2K 144   // padded LDS leading dim for W2^T
#define NE4 (N_EDGES / 4)        // 200000 int4 edge chunks (exact)
#define CPAD 8    // cnt padding stride (ints)
#define NSEGS 4                  // edge segments per window
#define SBLK (NWIN * NSEGS)      // 32 scatter blocks
#define CSEG (NE4 / NSEGS)       // 50000 int4 chunks per segment (exact)
#define EWBLK 13                 // ceil(12800/1024) EW1 blocks

using bf16x8  = __attribute__((ext_vector_type(8))) __bf16;
using floatx4 = __attribute__((ext_vector_type(4))) float;

__device__ __forceinline__ unsigned short f2bf(float f) {
    unsigned u = __float_as_uint(f);
    return (unsigned short)((u + 0x7FFF + ((u >> 16) & 1)) >> 16);  // RNE
}

// ---------------- scatter v2: LDS-binned, range-reservation (4x fewer global atomics) --
// blocks [0,32): 8 windows x 4 edge-segments. Phase1: LDS degree count (ds_add).
// Phase2: ONE global atomicAdd per touched node reserves a slot range (~6.1K/block).
// Phase3: L2-warm re-scan, place via LDS cursors (= reserved base). Blocks of window w
// land on XCD w (blockIdx%8 dispatch) -> cnt/slots/cursors XCD-local.
// blocks [32,45): EW1 = emb@W1. block 45: starts[] + out[]=fcb.
__global__ __launch_bounds__(1024) void k_scatter(const int* __restrict__ src,
                                                  const int* __restrict__ dst,
                                                  const int* __restrict__ batch,
                                                  const float* __restrict__ emb,
                                                  const float* __restrict__ W1,
                                                  const float* __restrict__ fcb,
                                                  int* __restrict__ cnt,
                                                  int* __restrict__ slots,
                                                  float* __restrict__ EW1,
                                                  int* __restrict__ starts,
                                                  float* __restrict__ out) {
    __shared__ int lcnt[WSZ];   // 25000 B: degree count, then placement cursor
    int t = threadIdx.x;
    if (blockIdx.x < SBLK) {
        int w = blockIdx.x & (NWIN - 1);
        int seg = blockIdx.x >> 3;
        int lo = w * WSZ;
        for (int n = t; n < WSZ; n += 1024) lcnt[n] = 0;
        __syncthreads();
        int c0 = seg * CSEG, c1 = c0 + CSEG;
        // phase 1: count
        for (int e4 = c0 + t; e4 < c1; e4 += 1024) {
            int4 d4 = ((const int4*)dst)[e4];
            #pragma unroll
            for (int c = 0; c < 4; c++) {
                int d = (&d4.x)[c] - lo;
                if ((unsigned)d < (unsigned)WSZ) atomicAdd(&lcnt[d], 1);
            }
        }
        __syncthreads();
        // phase 2: reserve ranges (global atomic only for touched nodes)
        for (int n = t; n < WSZ; n += 1024) {
            int c = lcnt[n];
            lcnt[n] = (c > 0) ? atomicAdd(&cnt[(lo + n) * CPAD], c) : 0;
        }
        __syncthreads();
        // phase 3: place (LDS cursor starts at reserved base)
        for (int e4 = c0 + t; e4 < c1; e4 += 1024) {
            int4 d4 = ((const int4*)dst)[e4];
            int e = e4 * 4;
            #pragma unroll
            for (int c = 0; c < 4; c++) {
                int d = (&d4.x)[c] - lo;
                if ((unsigned)d < (unsigned)WSZ) {
                    int pos = atomicAdd(&lcnt[d], 1);
                    slots[(size_t)(lo + d) * CAP + pos] = src[e + c];
                }
            }
        }
    } else if (blockIdx.x < SBLK + EWBLK) {
        int idx = (blockIdx.x - SBLK) * 1024 + t;
        if (idx < VOCAB * DIM) {
            int r = idx >> 7, c = idx & 127;
            float acc = 0.f;
            for (int k = 0; k < DIM; k++) acc += emb[r * DIM + k] * W1[k * DIM + c];
            EW1[idx] = acc;
        }
    } else {
        for (int g = t; g <= N_GRAPHS; g += 1024) {
            int lo = 0, hi = N_NODES;
            while (lo < hi) { int mid = (lo + hi) >> 1; if (batch[mid] < g) lo = mid + 1; else hi = mid; }
            starts[g] = lo;
        }
        float fb = fcb[0];
        for (int g = t; g < N_GRAPHS; g += 1024) out[g] = fb;
    }
}

// ---------------- layer-1 agg + one-pass LN + ReLU, cross-node pipelined ----------------
__global__ __launch_bounds__(512) void k_agg1(
    const float* __restrict__ EW1, const int* __restrict__ x,
    const int* __restrict__ cnt, const int* __restrict__ slots,
    const float* __restrict__ b1, const float* __restrict__ g1,
    const float* __restrict__ be1, unsigned* __restrict__ h1b) {
    __shared__ unsigned ew[VOCAB * 64];  // bf16x2 packed, 25600 B
    for (int idx = threadIdx.x; idx < VOCAB * 64; idx += blockDim.x) {
        float2 v = ((const float2*)EW1)[idx];
        ew[idx] = (unsigned)f2bf(v.x) | ((unsigned)f2bf(v.y) << 16);
    }
    __syncthreads();
    int lane = threadIdx.x & 63;
    int wave = (blockIdx.x * blockDim.x + threadIdx.x) >> 6;
    int nw = (gridDim.x * blockDim.x) >> 6;
    float2 bb = make_float2(b1[2 * lane], b1[2 * lane + 1]);
    float2 gg = make_float2(g1[2 * lane], g1[2 * lane + 1]);
    float2 eb = make_float2(be1[2 * lane], be1[2 * lane + 1]);

    int i = wave;
    if (i >= N_NODES) return;

    int cn, xi; float di; unsigned myw;
    {
        int iu = __builtin_amdgcn_readfirstlane(i);
        cn = cnt[iu * CPAD]; di = rsqrtf((float)cn + 1.f); xi = x[iu];
        int s = slots[(size_t)iu * CAP + lane];
        unsigned ss = min((unsigned)s, (unsigned)(N_NODES - 1));
        float ds = rsqrtf((float)cnt[ss * CPAD] + 1.f);
        myw = ((unsigned)__half_as_ushort(__float2half_rn(ds)) << 16) | (unsigned)x[ss];
    }
    while (i < N_NODES) {
        int inext = i + nw;
        int cnN = 0, xiN = 0; float diN = 0.f; unsigned mywN = 0;
        if (inext < N_NODES) {
            int iun = __builtin_amdgcn_readfirstlane(inext);
            cnN = cnt[iun * CPAD]; diN = rsqrtf((float)cnN + 1.f); xiN = x[iun];
            int s = slots[(size_t)iun * CAP + lane];
            unsigned ss = min((unsigned)s, (unsigned)(N_NODES - 1));
            float ds = rsqrtf((float)cnt[ss * CPAD] + 1.f);
            mywN = ((unsigned)__half_as_ushort(__float2half_rn(ds)) << 16) | (unsigned)x[ss];
        }
        int iu = __builtin_amdgcn_readfirstlane(i);
        unsigned e0 = ew[xi * 64 + lane];
        float ax = di * __uint_as_float(e0 << 16);
        float ay = di * __uint_as_float(e0 & 0xFFFF0000u);  // self-loop
        int j = 0;
        for (; j + 8 <= cn; j += 8) {
            #pragma unroll
            for (int u = 0; u < 8; u++) {
                unsigned w = (unsigned)__shfl((int)myw, j + u, 64);
                int xv = (int)(w & 0xFFFFu);
                float ds = __half2float(__ushort_as_half((unsigned short)(w >> 16)));
                unsigned es = ew[xv * 64 + lane];
                ax += ds * __uint_as_float(es << 16);
                ay += ds * __uint_as_float(es & 0xFFFF0000u);
            }
        }
        for (; j < cn; j++) {
            unsigned w = (unsigned)__shfl((int)myw, j, 64);
            int xv = (int)(w & 0xFFFFu);
            float ds = __half2float(__ushort_as_half((unsigned short)(w >> 16)));
            unsigned es = ew[xv * 64 + lane];
            ax += ds * __uint_as_float(es << 16);
            ay += ds * __uint_as_float(es & 0xFFFF0000u);
        }
        float a0 = di * ax + bb.x, a1 = di * ay + bb.y;
        float s = a0 + a1, q = a0 * a0 + a1 * a1;
        #pragma unroll
        for (int m = 1; m < 64; m <<= 1) {
            s += __shfl_xor(s, m, 64);
            q += __shfl_xor(q, m, 64);
        }
        float mu = s * (1.f / 128.f);
        float r = rsqrtf(q * (1.f / 128.f) - mu * mu + LN_EPS);
        float o0 = fmaxf((a0 - mu) * r * gg.x + eb.x, 0.f);
        float o1 = fmaxf((a1 - mu) * r * gg.y + eb.y, 0.f);
        h1b[(size_t)iu * 64 + lane] = (unsigned)f2bf(o0) | ((unsigned)f2bf(o1) << 16);
        i = inext; cn = cnN; di = diN; xi = xiN; myw = mywN;
    }
}

// ---------------- v2 = bf16( dinv * (h1 @ W2) ), MFMA 16x16x32 bf16 ----------------
__global__ __launch_bounds__(512) void k_mm2(
    const unsigned short* __restrict__ h1b, const float* __restrict__ W2,
    const int* __restrict__ cnt, unsigned short* __restrict__ v2b) {
    __shared__ unsigned short w2t[DIM * W2K];  // 36864 B
    int t = threadIdx.x;
    for (int idx = t * 4; idx < DIM * DIM; idx += 2048) {
        int k = idx >> 7, n = idx & 127;
        float4 v = *(const float4*)&W2[idx];
        w2t[(n + 0) * W2K + k] = f2bf(v.x);
        w2t[(n + 1) * W2K + k] = f2bf(v.y);
        w2t[(n + 2) * W2K + k] = f2bf(v.z);
        w2t[(n + 3) * W2K + k] = f2bf(v.w);
    }
    __syncthreads();
    int lane = t & 63, wv = t >> 6;
    int m = lane & 15, quad = lane >> 4;
    const int NT = N_NODES / 16;  // 3125 row-tiles (exact)
    for (int tile = blockIdx.x * 8 + wv; tile < NT; tile += gridDim.x * 8) {
        const unsigned short* arow = &h1b[(size_t)(tile * 16 + m) * DIM + quad * 8];
        bf16x8 a0 = *(const bf16x8*)(arow);
        bf16x8 a1 = *(const bf16x8*)(arow + 32);
        bf16x8 a2 = *(const bf16x8*)(arow + 64);
        bf16x8 a3 = *(const bf16x8*)(arow + 96);
        int r0 = tile * 16 + quad * 4;
        float dv0 = rsqrtf((float)cnt[(r0 + 0) * CPAD] + 1.f);
        float dv1 = rsqrtf((float)cnt[(r0 + 1) * CPAD] + 1.f);
        float dv2 = rsqrtf((float)cnt[(r0 + 2) * CPAD] + 1.f);
        float dv3 = rsqrtf((float)cnt[(r0 + 3) * CPAD] + 1.f);
        #pragma unroll
        for (int nt = 0; nt < 8; nt++) {
            const unsigned short* brow = &w2t[(nt * 16 + m) * W2K + quad * 8];
            bf16x8 b0 = *(const bf16x8*)(brow);
            bf16x8 b1 = *(const bf16x8*)(brow + 32);
            bf16x8 b2 = *(const bf16x8*)(brow + 64);
            bf16x8 b3 = *(const bf16x8*)(brow + 96);
            floatx4 c = {0.f, 0.f, 0.f, 0.f};
            c = __builtin_amdgcn_mfma_f32_16x16x32_bf16(a0, b0, c, 0, 0, 0);
            c = __builtin_amdgcn_mfma_f32_16x16x32_bf16(a1, b1, c, 0, 0, 0);
            c = __builtin_amdgcn_mfma_f32_16x16x32_bf16(a2, b2, c, 0, 0, 0);
            c = __builtin_amdgcn_mfma_f32_16x16x32_bf16(a3, b3, c, 0, 0, 0);
            int col = nt * 16 + m;  // C/D: col=lane&15, row=quad*4+reg (m89/m91)
            v2b[(size_t)(r0 + 0) * DIM + col] = f2bf(dv0 * c[0]);
            v2b[(size_t)(r0 + 1) * DIM + col] = f2bf(dv1 * c[1]);
            v2b[(size_t)(r0 + 2) * DIM + col] = f2bf(dv2 * c[2]);
            v2b[(size_t)(r0 + 3) * DIM + col] = f2bf(dv3 * c[3]);
        }
    }
}

// ---------------- layer-2 agg + one-pass LN + fc dot, pipelined + scalar slot indices --
__global__ __launch_bounds__(256) void k_agg2(
    const unsigned* __restrict__ v2u, const int* __restrict__ cnt,
    const int* __restrict__ slots, const int* __restrict__ batch,
    const int* __restrict__ starts,
    const float* __restrict__ b2, const float* __restrict__ g2,
    const float* __restrict__ be2, const float* __restrict__ fcW,
    float* __restrict__ out) {
    int lane = threadIdx.x & 63;
    int wave = (blockIdx.x * blockDim.x + threadIdx.x) >> 6;
    int i0 = wave * SEG;
    if (i0 >= N_NODES) return;

    float2 bb = make_float2(b2[2 * lane], b2[2 * lane + 1]);
    float2 gg = make_float2(g2[2 * lane], g2[2 * lane + 1]);
    float2 eb = make_float2(be2[2 * lane], be2[2 * lane + 1]);
    float2 fw = ((const float2*)fcW)[lane];

    float dv = 0.f; int bv = 0, cv = 0;
    if (lane < SEG) {
        cv = cnt[(i0 + lane) * CPAD]; dv = rsqrtf((float)cv + 1.f); bv = batch[i0 + lane];
    }

    float pz = 0.f;
    int cur_g = __builtin_amdgcn_readfirstlane(__shfl(bv, 0, 64));
    float pax = 0.f, pay = 0.f, pdi = 0.f; int pg = 0;

    auto finish = [&](float ax, float ay, float di, int g) {
        float a0 = di * ax + bb.x, a1 = di * ay + bb.y;
        float s = a0 + a1, q = a0 * a0 + a1 * a1;
        #pragma unroll
        for (int m = 1; m < 64; m <<= 1) {
            s += __shfl_xor(s, m, 64);
            q += __shfl_xor(q, m, 64);
        }
        float mu = s * (1.f / 128.f);
        float r = rsqrtf(q * (1.f / 128.f) - mu * mu + LN_EPS);
        float o0 = fmaxf((a0 - mu) * r * gg.x + eb.x, 0.f);
        float o1 = fmaxf((a1 - mu) * r * gg.y + eb.y, 0.f);
        float z = o0 * fw.x + o1 * fw.y;
        #pragma unroll
        for (int m = 1; m < 64; m <<= 1) z += __shfl_xor(z, m, 64);
        if (g != cur_g) {
            if (lane == 0) {
                float c = (float)(starts[cur_g + 1] - starts[cur_g]);
                if (c < 1.f) c = 1.f;
                atomicAdd(&out[cur_g], pz / c);
            }
            pz = 0.f; cur_g = g;
        }
        pz += z;
    };

    #pragma unroll
    for (int k = 0; k < SEG; k++) {
        int iu = __builtin_amdgcn_readfirstlane(i0 + k);
        int cn = __builtin_amdgcn_readfirstlane(__shfl(cv, k, 64));
        float di = __shfl(dv, k, 64);
        int g = __builtin_amdgcn_readfirstlane(__shfl(bv, k, 64));
        const int* srow = slots + (size_t)iu * CAP;

        int sx[32];
        #pragma unroll
        for (int u = 0; u < 32; u++) sx[u] = srow[u];

        unsigned u0 = v2u[(size_t)iu * 64 + lane];
        unsigned uvv[32];
        #pragma unroll
        for (int c8 = 0; c8 < 4; c8++) {
            if (cn > c8 * 8) {
                #pragma unroll
                for (int u = 0; u < 8; u++) {
                    int idx = c8 * 8 + u;
                    int s = (idx < cn) ? sx[idx] : 0;
                    uvv[idx] = v2u[(size_t)s * 64 + lane];
                }
            }
        }

        if (k > 0) finish(pax, pay, pdi, pg);

        float ax = __uint_as_float(u0 << 16);
        float ay = __uint_as_float(u0 & 0xFFFF0000u);
        #pragma unroll
        for (int c8 = 0; c8 < 4; c8++) {
            if (cn > c8 * 8) {
                #pragma unroll
                for (int u = 0; u < 8; u++) {
                    int idx = c8 * 8 + u;
                    unsigned vv = (idx < cn) ? uvv[idx] : 0u;
                    ax += __uint_as_float(vv << 16);
                    ay += __uint_as_float(vv & 0xFFFF0000u);
                }
            }
        }
        if (cn > 32) {
            for (int j = 32; j < cn; j++) {
                int s = srow[j];
                unsigned vv = v2u[(size_t)s * 64 + lane];
                ax += __uint_as_float(vv << 16);
                ay += __uint_as_float(vv & 0xFFFF0000u);
            }
        }
        pax = ax; pay = ay; pdi = di; pg = g;
    }
    finish(pax, pay, pdi, pg);
    if (lane == 0) {
        float c = (float)(starts[cur_g + 1] - starts[cur_g]);
        if (c < 1.f) c = 1.f;
        atomicAdd(&out[cur_g], pz / c);
    }
}

extern "C" void kernel_launch(void* const* d_in, const int* in_sizes, int n_in,
                              void* d_out, int out_size, void* d_ws, size_t ws_size,
                              hipStream_t stream) {
    (void)in_sizes; (void)n_in; (void)out_size; (void)ws_size;
    const int* x    = (const int*)d_in[0];
    const int* src  = (const int*)d_in[1];
    const int* dst  = src + N_EDGES;
    const int* batch = (const int*)d_in[2];
    const float* emb = (const float*)d_in[3];
    const float* W1  = (const float*)d_in[4];
    const float* b1  = (const float*)d_in[5];
    const float* g1  = (const float*)d_in[6];
    const float* be1 = (const float*)d_in[7];
    const float* W2  = (const float*)d_in[8];
    const float* b2  = (const float*)d_in[9];
    const float* g2  = (const float*)d_in[10];
    const float* be2 = (const float*)d_in[11];
    const float* fcW = (const float*)d_in[12];
    const float* fcb = (const float*)d_in[13];
    float* out = (float*)d_out;

    char* wsp = (char*)d_ws;
    size_t off = 0;
    auto alloc = [&](size_t bytes) -> void* {
        void* p = wsp + off;
        off += (bytes + 15) & ~(size_t)15;
        return p;
    };
    // ---- zeroed region ----
    int* cnt = (int*)alloc((size_t)N_NODES * CPAD * 4);  // 1.6 MB line-padded counters
    size_t zero_bytes = off;
    // ---- scratch ----
    int*   slots  = (int*)alloc((size_t)N_NODES * CAP * 4);  // 12.8 MB
    float* EW1    = (float*)alloc(VOCAB * DIM * 4);
    int*   starts = (int*)alloc((N_GRAPHS + 1) * 4);
    unsigned short* h1b = (unsigned short*)alloc((size_t)N_NODES * DIM * 2);
    unsigned short* v2b = (unsigned short*)alloc((size_t)N_NODES * DIM * 2);

    hipMemsetAsync(d_ws, 0, zero_bytes, stream);

    k_scatter<<<SBLK + EWBLK + 1, 1024, 0, stream>>>(src, dst, batch, emb, W1, fcb,
                                                     cnt, slots, EW1, starts, out);
    k_agg1<<<1024, 512, 0, stream>>>(EW1, x, cnt, slots, b1, g1, be1, (unsigned*)h1b);
    k_mm2<<<391, 512, 0, stream>>>(h1b, W2, cnt, v2b);
    {
        int nwaves = (N_NODES + SEG - 1) / SEG;          // 12500
        int nblocks = (nwaves + 3) / 4;                  // 3125 blocks, 4 waves each
        k_agg2<<<nblocks, 256, 0, stream>>>((const unsigned*)v2b, cnt, slots, batch,
                                            starts, b2, g2, be2, fcW, out);
    }
}

// Round 8
// 221.598 us; speedup vs baseline: 1.2867x; 1.2867x over previous
//
#include <hip/hip_runtime.h>
#include <hip/hip_fp16.h>
#include <math.h>

#define N_NODES 50000
#define N_EDGES 800000
#define VOCAB 100
#define DIM 128
#define N_GRAPHS 512
#define LN_EPS 1e-5f
#define CAP 64    // slot capacity per node (deg~Poisson(16); P(>=64)~e^-125)
#define SEG 4     // nodes per wave in k_agg2 (50000 % 4 == 0)
#define NWIN 8    // dst windows (== XCDs)
#define WSZ ((N_NODES + NWIN - 1) / NWIN)
#define W2K 144   // padded LDS leading dim for W2^T
#define NSCAT 2048               // scatter blocks (multiple of 8)
#define NE4 (N_EDGES / 4)        // 200000 int4 edge chunks (exact)
#define CPAD 8    // cnt padding stride (ints): 32 B/counter
#define MMGRID 512               // k_mm2 blocks: 2/CU, balanced via transposed tile map

using bf16x8  = __attribute__((ext_vector_type(8))) __bf16;
using floatx4 = __attribute__((ext_vector_type(4))) float;

__device__ __forceinline__ unsigned short f2bf(float f) {
    unsigned u = __float_as_uint(f);
    return (unsigned short)((u + 0x7FFF + ((u >> 16) & 1)) >> 16);  // RNE
}

// ---------------- scatter (XCD-windowed, int4 dst+src scan) + EW1 + starts + out-init --
// src loaded unconditionally as int4: sequential/prefetchable, and the 4 per-chunk
// atomic->store chains become independent (src no longer in the dependent path).
__global__ __launch_bounds__(256) void k_scatter(const int* __restrict__ src,
                                                 const int* __restrict__ dst,
                                                 const int* __restrict__ batch,
                                                 const float* __restrict__ emb,
                                                 const float* __restrict__ W1,
                                                 const float* __restrict__ fcb,
                                                 int* __restrict__ cnt,
                                                 int* __restrict__ slots,
                                                 float* __restrict__ EW1,
                                                 int* __restrict__ starts,
                                                 float* __restrict__ out) {
    int t = threadIdx.x;
    if (blockIdx.x < NSCAT) {
        int w = blockIdx.x & (NWIN - 1);
        int bg = blockIdx.x >> 3;
        int lo = w * WSZ, hi = lo + WSZ; if (hi > N_NODES) hi = N_NODES;
        int stride = (NSCAT >> 3) * 256;  // 65536 threads per window group
        for (int e4 = bg * 256 + t; e4 < NE4; e4 += stride) {
            int4 d4 = ((const int4*)dst)[e4];
            int4 s4 = ((const int4*)src)[e4];
            #pragma unroll
            for (int c = 0; c < 4; c++) {
                int d = (&d4.x)[c];
                if (d >= lo && d < hi) {
                    int pos = atomicAdd(&cnt[d * CPAD], 1);
                    slots[d * CAP + pos] = (&s4.x)[c];
                }
            }
        }
    } else if (blockIdx.x < NSCAT + 50) {
        int idx = (blockIdx.x - NSCAT) * 256 + t;   // < 12800 always
        int r = idx >> 7, c = idx & 127;
        float acc = 0.f;
        for (int k = 0; k < DIM; k++) acc += emb[r * DIM + k] * W1[k * DIM + c];
        EW1[idx] = acc;
    } else {
        for (int g = t; g <= N_GRAPHS; g += 256) {
            int lo = 0, hi = N_NODES;
            while (lo < hi) { int mid = (lo + hi) >> 1; if (batch[mid] < g) lo = mid + 1; else hi = mid; }
            starts[g] = lo;
        }
        float fb = fcb[0];
        for (int g = t; g < N_GRAPHS; g += 256) out[g] = fb;
    }
}

// ---------------- layer-1 agg + one-pass LN + ReLU, cross-node pipelined ----------------
__global__ __launch_bounds__(512) void k_agg1(
    const float* __restrict__ EW1, const int* __restrict__ x,
    const int* __restrict__ cnt, const int* __restrict__ slots,
    const float* __restrict__ b1, const float* __restrict__ g1,
    const float* __restrict__ be1, unsigned* __restrict__ h1b) {
    __shared__ unsigned ew[VOCAB * 64];  // bf16x2 packed, 25600 B
    for (int idx = threadIdx.x; idx < VOCAB * 64; idx += blockDim.x) {
        float2 v = ((const float2*)EW1)[idx];
        ew[idx] = (unsigned)f2bf(v.x) | ((unsigned)f2bf(v.y) << 16);
    }
    __syncthreads();
    int lane = threadIdx.x & 63;
    int wave = (blockIdx.x * blockDim.x + threadIdx.x) >> 6;
    int nw = (gridDim.x * blockDim.x) >> 6;
    float2 bb = make_float2(b1[2 * lane], b1[2 * lane + 1]);
    float2 gg = make_float2(g1[2 * lane], g1[2 * lane + 1]);
    float2 eb = make_float2(be1[2 * lane], be1[2 * lane + 1]);

    int i = wave;
    if (i >= N_NODES) return;

    int cn, xi; float di; unsigned myw;
    {
        int iu = __builtin_amdgcn_readfirstlane(i);
        cn = cnt[iu * CPAD]; di = rsqrtf((float)cn + 1.f); xi = x[iu];
        int s = slots[(size_t)iu * CAP + lane];
        unsigned ss = min((unsigned)s, (unsigned)(N_NODES - 1));
        float ds = rsqrtf((float)cnt[ss * CPAD] + 1.f);
        myw = ((unsigned)__half_as_ushort(__float2half_rn(ds)) << 16) | (unsigned)x[ss];
    }
    while (i < N_NODES) {
        int inext = i + nw;
        int cnN = 0, xiN = 0; float diN = 0.f; unsigned mywN = 0;
        if (inext < N_NODES) {
            int iun = __builtin_amdgcn_readfirstlane(inext);
            cnN = cnt[iun * CPAD]; diN = rsqrtf((float)cnN + 1.f); xiN = x[iun];
            int s = slots[(size_t)iun * CAP + lane];
            unsigned ss = min((unsigned)s, (unsigned)(N_NODES - 1));
            float ds = rsqrtf((float)cnt[ss * CPAD] + 1.f);
            mywN = ((unsigned)__half_as_ushort(__float2half_rn(ds)) << 16) | (unsigned)x[ss];
        }
        int iu = __builtin_amdgcn_readfirstlane(i);
        unsigned e0 = ew[xi * 64 + lane];
        float ax = di * __uint_as_float(e0 << 16);
        float ay = di * __uint_as_float(e0 & 0xFFFF0000u);  // self-loop
        int j = 0;
        for (; j + 8 <= cn; j += 8) {
            #pragma unroll
            for (int u = 0; u < 8; u++) {
                unsigned w = (unsigned)__shfl((int)myw, j + u, 64);
                int xv = (int)(w & 0xFFFFu);
                float ds = __half2float(__ushort_as_half((unsigned short)(w >> 16)));
                unsigned es = ew[xv * 64 + lane];
                ax += ds * __uint_as_float(es << 16);
                ay += ds * __uint_as_float(es & 0xFFFF0000u);
            }
        }
        for (; j < cn; j++) {
            unsigned w = (unsigned)__shfl((int)myw, j, 64);
            int xv = (int)(w & 0xFFFFu);
            float ds = __half2float(__ushort_as_half((unsigned short)(w >> 16)));
            unsigned es = ew[xv * 64 + lane];
            ax += ds * __uint_as_float(es << 16);
            ay += ds * __uint_as_float(es & 0xFFFF0000u);
        }
        float a0 = di * ax + bb.x, a1 = di * ay + bb.y;
        float s = a0 + a1, q = a0 * a0 + a1 * a1;
        #pragma unroll
        for (int m = 1; m < 64; m <<= 1) {
            s += __shfl_xor(s, m, 64);
            q += __shfl_xor(q, m, 64);
        }
        float mu = s * (1.f / 128.f);
        float r = rsqrtf(q * (1.f / 128.f) - mu * mu + LN_EPS);
        float o0 = fmaxf((a0 - mu) * r * gg.x + eb.x, 0.f);
        float o1 = fmaxf((a1 - mu) * r * gg.y + eb.y, 0.f);
        h1b[(size_t)iu * 64 + lane] = (unsigned)f2bf(o0) | ((unsigned)f2bf(o1) << 16);
        i = inext; cn = cnN; di = diN; xi = xiN; myw = mywN;
    }
}

// ---------------- v2 = bf16( dinv * (h1 @ W2) ), MFMA 16x16x32 bf16 ----------------
// Balanced tile map: tile = wv*grid + blockIdx (transposed) -> every block gets
// 6-7 tiles; old map (blockIdx*8+wv, 391 blocks) left 121 CUs at half load.
__global__ __launch_bounds__(512) void k_mm2(
    const unsigned short* __restrict__ h1b, const float* __restrict__ W2,
    const int* __restrict__ cnt, unsigned short* __restrict__ v2b) {
    __shared__ unsigned short w2t[DIM * W2K];  // 36864 B
    int t = threadIdx.x;
    for (int idx = t * 4; idx < DIM * DIM; idx += 2048) {
        int k = idx >> 7, n = idx & 127;
        float4 v = *(const float4*)&W2[idx];
        w2t[(n + 0) * W2K + k] = f2bf(v.x);
        w2t[(n + 1) * W2K + k] = f2bf(v.y);
        w2t[(n + 2) * W2K + k] = f2bf(v.z);
        w2t[(n + 3) * W2K + k] = f2bf(v.w);
    }
    __syncthreads();
    int lane = t & 63, wv = t >> 6;
    int m = lane & 15, quad = lane >> 4;
    const int NT = N_NODES / 16;  // 3125 row-tiles (exact)
    for (int tile = wv * (int)gridDim.x + (int)blockIdx.x; tile < NT;
         tile += 8 * (int)gridDim.x) {
        const unsigned short* arow = &h1b[(size_t)(tile * 16 + m) * DIM + quad * 8];
        bf16x8 a0 = *(const bf16x8*)(arow);
        bf16x8 a1 = *(const bf16x8*)(arow + 32);
        bf16x8 a2 = *(const bf16x8*)(arow + 64);
        bf16x8 a3 = *(const bf16x8*)(arow + 96);
        int r0 = tile * 16 + quad * 4;
        float dv0 = rsqrtf((float)cnt[(r0 + 0) * CPAD] + 1.f);
        float dv1 = rsqrtf((float)cnt[(r0 + 1) * CPAD] + 1.f);
        float dv2 = rsqrtf((float)cnt[(r0 + 2) * CPAD] + 1.f);
        float dv3 = rsqrtf((float)cnt[(r0 + 3) * CPAD] + 1.f);
        #pragma unroll
        for (int nt = 0; nt < 8; nt++) {
            const unsigned short* brow = &w2t[(nt * 16 + m) * W2K + quad * 8];
            bf16x8 b0 = *(const bf16x8*)(brow);
            bf16x8 b1 = *(const bf16x8*)(brow + 32);
            bf16x8 b2 = *(const bf16x8*)(brow + 64);
            bf16x8 b3 = *(const bf16x8*)(brow + 96);
            floatx4 c = {0.f, 0.f, 0.f, 0.f};
            c = __builtin_amdgcn_mfma_f32_16x16x32_bf16(a0, b0, c, 0, 0, 0);
            c = __builtin_amdgcn_mfma_f32_16x16x32_bf16(a1, b1, c, 0, 0, 0);
            c = __builtin_amdgcn_mfma_f32_16x16x32_bf16(a2, b2, c, 0, 0, 0);
            c = __builtin_amdgcn_mfma_f32_16x16x32_bf16(a3, b3, c, 0, 0, 0);
            int col = nt * 16 + m;  // C/D: col=lane&15, row=quad*4+reg (m89/m91)
            v2b[(size_t)(r0 + 0) * DIM + col] = f2bf(dv0 * c[0]);
            v2b[(size_t)(r0 + 1) * DIM + col] = f2bf(dv1 * c[1]);
            v2b[(size_t)(r0 + 2) * DIM + col] = f2bf(dv2 * c[2]);
            v2b[(size_t)(r0 + 3) * DIM + col] = f2bf(dv3 * c[3]);
        }
    }
}

// ---------------- layer-2 agg + one-pass LN + fc dot, pipelined + scalar slot indices --
__global__ __launch_bounds__(256) void k_agg2(
    const unsigned* __restrict__ v2u, const int* __restrict__ cnt,
    const int* __restrict__ slots, const int* __restrict__ batch,
    const int* __restrict__ starts,
    const float* __restrict__ b2, const float* __restrict__ g2,
    const float* __restrict__ be2, const float* __restrict__ fcW,
    float* __restrict__ out) {
    int lane = threadIdx.x & 63;
    int wave = (blockIdx.x * blockDim.x + threadIdx.x) >> 6;
    int i0 = wave * SEG;
    if (i0 >= N_NODES) return;

    float2 bb = make_float2(b2[2 * lane], b2[2 * lane + 1]);
    float2 gg = make_float2(g2[2 * lane], g2[2 * lane + 1]);
    float2 eb = make_float2(be2[2 * lane], be2[2 * lane + 1]);
    float2 fw = ((const float2*)fcW)[lane];

    float dv = 0.f; int bv = 0, cv = 0;
    if (lane < SEG) {
        cv = cnt[(i0 + lane) * CPAD]; dv = rsqrtf((float)cv + 1.f); bv = batch[i0 + lane];
    }

    float pz = 0.f;
    int cur_g = __builtin_amdgcn_readfirstlane(__shfl(bv, 0, 64));
    float pax = 0.f, pay = 0.f, pdi = 0.f; int pg = 0;

    auto finish = [&](float ax, float ay, float di, int g) {
        float a0 = di * ax + bb.x, a1 = di * ay + bb.y;
        float s = a0 + a1, q = a0 * a0 + a1 * a1;
        #pragma unroll
        for (int m = 1; m < 64; m <<= 1) {
            s += __shfl_xor(s, m, 64);
            q += __shfl_xor(q, m, 64);
        }
        float mu = s * (1.f / 128.f);
        float r = rsqrtf(q * (1.f / 128.f) - mu * mu + LN_EPS);
        float o0 = fmaxf((a0 - mu) * r * gg.x + eb.x, 0.f);
        float o1 = fmaxf((a1 - mu) * r * gg.y + eb.y, 0.f);
        float z = o0 * fw.x + o1 * fw.y;
        #pragma unroll
        for (int m = 1; m < 64; m <<= 1) z += __shfl_xor(z, m, 64);
        if (g != cur_g) {
            if (lane == 0) {
                float c = (float)(starts[cur_g + 1] - starts[cur_g]);
                if (c < 1.f) c = 1.f;
                atomicAdd(&out[cur_g], pz / c);
            }
            pz = 0.f; cur_g = g;
        }
        pz += z;
    };

    #pragma unroll
    for (int k = 0; k < SEG; k++) {
        int iu = __builtin_amdgcn_readfirstlane(i0 + k);
        int cn = __builtin_amdgcn_readfirstlane(__shfl(cv, k, 64));
        float di = __shfl(dv, k, 64);
        int g = __builtin_amdgcn_readfirstlane(__shfl(bv, k, 64));
        const int* srow = slots + (size_t)iu * CAP;

        int sx[32];
        #pragma unroll
        for (int u = 0; u < 32; u++) sx[u] = srow[u];

        unsigned u0 = v2u[(size_t)iu * 64 + lane];
        unsigned uvv[32];
        #pragma unroll
        for (int c8 = 0; c8 < 4; c8++) {
            if (cn > c8 * 8) {
                #pragma unroll
                for (int u = 0; u < 8; u++) {
                    int idx = c8 * 8 + u;
                    int s = (idx < cn) ? sx[idx] : 0;
                    uvv[idx] = v2u[(size_t)s * 64 + lane];
                }
            }
        }

        if (k > 0) finish(pax, pay, pdi, pg);

        float ax = __uint_as_float(u0 << 16);
        float ay = __uint_as_float(u0 & 0xFFFF0000u);
        #pragma unroll
        for (int c8 = 0; c8 < 4; c8++) {
            if (cn > c8 * 8) {
                #pragma unroll
                for (int u = 0; u < 8; u++) {
                    int idx = c8 * 8 + u;
                    unsigned vv = (idx < cn) ? uvv[idx] : 0u;
                    ax += __uint_as_float(vv << 16);
                    ay += __uint_as_float(vv & 0xFFFF0000u);
                }
            }
        }
        if (cn > 32) {
            for (int j = 32; j < cn; j++) {
                int s = srow[j];
                unsigned vv = v2u[(size_t)s * 64 + lane];
                ax += __uint_as_float(vv << 16);
                ay += __uint_as_float(vv & 0xFFFF0000u);
            }
        }
        pax = ax; pay = ay; pdi = di; pg = g;
    }
    finish(pax, pay, pdi, pg);
    if (lane == 0) {
        float c = (float)(starts[cur_g + 1] - starts[cur_g]);
        if (c < 1.f) c = 1.f;
        atomicAdd(&out[cur_g], pz / c);
    }
}

extern "C" void kernel_launch(void* const* d_in, const int* in_sizes, int n_in,
                              void* d_out, int out_size, void* d_ws, size_t ws_size,
                              hipStream_t stream) {
    (void)in_sizes; (void)n_in; (void)out_size; (void)ws_size;
    const int* x    = (const int*)d_in[0];
    const int* src  = (const int*)d_in[1];
    const int* dst  = src + N_EDGES;
    const int* batch = (const int*)d_in[2];
    const float* emb = (const float*)d_in[3];
    const float* W1  = (const float*)d_in[4];
    const float* b1  = (const float*)d_in[5];
    const float* g1  = (const float*)d_in[6];
    const float* be1 = (const float*)d_in[7];
    const float* W2  = (const float*)d_in[8];
    const float* b2  = (const float*)d_in[9];
    const float* g2  = (const float*)d_in[10];
    const float* be2 = (const float*)d_in[11];
    const float* fcW = (const float*)d_in[12];
    const float* fcb = (const float*)d_in[13];
    float* out = (float*)d_out;

    char* wsp = (char*)d_ws;
    size_t off = 0;
    auto alloc = [&](size_t bytes) -> void* {
        void* p = wsp + off;
        off += (bytes + 15) & ~(size_t)15;
        return p;
    };
    // ---- zeroed region ----
    int* cnt = (int*)alloc((size_t)N_NODES * CPAD * 4);  // 1.6 MB line-padded counters
    size_t zero_bytes = off;
    // ---- scratch ----
    int*   slots  = (int*)alloc((size_t)N_NODES * CAP * 4);  // 12.8 MB
    float* EW1    = (float*)alloc(VOCAB * DIM * 4);
    int*   starts = (int*)alloc((N_GRAPHS + 1) * 4);
    unsigned short* h1b = (unsigned short*)alloc((size_t)N_NODES * DIM * 2);
    unsigned short* v2b = (unsigned short*)alloc((size_t)N_NODES * DIM * 2);

    hipMemsetAsync(d_ws, 0, zero_bytes, stream);

    k_scatter<<<NSCAT + 50 + 1, 256, 0, stream>>>(src, dst, batch, emb, W1, fcb,
                                                  cnt, slots, EW1, starts, out);
    k_agg1<<<1024, 512, 0, stream>>>(EW1, x, cnt, slots, b1, g1, be1, (unsigned*)h1b);
    k_mm2<<<MMGRID, 512, 0, stream>>>(h1b, W2, cnt, v2b);
    {
        int nwaves = (N_NODES + SEG - 1) / SEG;          // 12500
        int nblocks = (nwaves + 3) / 4;                  // 3125 blocks, 4 waves each
        k_agg2<<<nblocks, 256, 0, stream>>>((const unsigned*)v2b, cnt, slots, batch,
                                            starts, b2, g2, be2, fcW, out);
    }
}